// Round 1
// baseline (436.238 us; speedup 1.0000x reference)
//
#include <hip/hip_runtime.h>
#include <cstdint>

#define F_H 200
#define F_W 200
#define D1  50176
#define NBOX 512
#define NHID 1024

typedef _Float16 f16;
typedef _Float16 half8 __attribute__((ext_vector_type(8)));
typedef float    f32x4 __attribute__((ext_vector_type(4)));

// ---------- helpers ----------
__device__ __forceinline__ void gload16(const void* g, void* l) {
  __builtin_amdgcn_global_load_lds((const __attribute__((address_space(1))) void*)g,
                                   (__attribute__((address_space(3))) void*)l,
                                   16, 0, 0);
}

// f32 -> f16 hi + f16 lo*2^-11 split; flush sub-normal hi so result is exact
// regardless of MFMA input-denormal behavior.
__device__ __forceinline__ void splitf16(float v, f16& h, f16& l) {
  f16 hh = (f16)v;
  float hf = (float)hh;
  if (fabsf(hf) < 6.1035156e-5f) hf = 0.f;
  h = (f16)hf;
  l = (f16)((v - hf) * 2048.f);
}

// ---------- ROI align + split ----------
__global__ __launch_bounds__(256) void k_roi(const float* __restrict__ feat,
                                             const float* __restrict__ prop,
                                             f16* __restrict__ xhi, f16* __restrict__ xlo) {
  uint32_t idx = blockIdx.x * 256u + threadIdx.x;      // < 512*50176 exactly
  uint32_t n = idx / D1;
  uint32_t rem = idx % D1;
  uint32_t c = rem / 196u;
  uint32_t r2 = rem % 196u;
  uint32_t i = r2 / 14u;
  uint32_t j = r2 % 14u;
  float b0 = prop[n * 4 + 0] * 0.25f, b1 = prop[n * 4 + 1] * 0.25f;
  float b2 = prop[n * 4 + 2] * 0.25f, b3 = prop[n * 4 + 3] * 0.25f;
  float tx = ((float)j + 0.5f) * (1.0f / 14.0f);
  float ty = ((float)i + 0.5f) * (1.0f / 14.0f);
  float xx = b0 + (b2 - b0) * tx;
  float yy = b1 + (b3 - b1) * ty;
  float x0f = floorf(xx), y0f = floorf(yy);
  float fx = xx - x0f, fy = yy - y0f;
  int x0 = (int)x0f; x0 = x0 < 0 ? 0 : (x0 > F_W - 1 ? F_W - 1 : x0);
  int y0 = (int)y0f; y0 = y0 < 0 ? 0 : (y0 > F_H - 1 ? F_H - 1 : y0);
  int x1 = x0 + 1 > F_W - 1 ? F_W - 1 : x0 + 1;
  int y1 = y0 + 1 > F_H - 1 ? F_H - 1 : y0 + 1;
  const float* fc = feat + (size_t)c * (F_H * F_W);
  float v00 = fc[y0 * F_W + x0], v01 = fc[y0 * F_W + x1];
  float v10 = fc[y1 * F_W + x0], v11 = fc[y1 * F_W + x1];
  float v = (1.f - fx) * (1.f - fy) * v00 + fx * (1.f - fy) * v01 +
            (1.f - fx) * fy * v10 + fx * fy * v11;
  f16 h, l; splitf16(v, h, l);
  xhi[idx] = h; xlo[idx] = l;
}

// ---------- pack [w_cls | w_reg | 0] -> [1024][512] and bias ----------
__global__ __launch_bounds__(256) void k_pack(const float* __restrict__ wc, const float* __restrict__ bc,
                                              const float* __restrict__ wr, const float* __restrict__ br,
                                              float* __restrict__ wh, float* __restrict__ bh) {
  uint32_t idx = blockIdx.x * 256u + threadIdx.x;
  if (idx < (uint32_t)NHID * 512u) {
    uint32_t k = idx >> 9, n = idx & 511u;
    float v = 0.f;
    if (n < 81u) v = wc[k * 81u + n];
    else if (n < 405u) v = wr[k * 324u + (n - 81u)];
    wh[idx] = v;
  } else if (idx < (uint32_t)NHID * 512u + 512u) {
    uint32_t n = idx - (uint32_t)NHID * 512u;
    float v = 0.f;
    if (n < 81u) v = bc[n];
    else if (n < 405u) v = br[n - 81u];
    bh[n] = v;
  }
}

// ---------- split-f16 GEMM: C_part[ks] = Ahi/lo[M,K] * B_f32[K,N] (tile 256x256, BK=32) ----------
__global__ __launch_bounds__(512, 2) void k_gemm(
    const f16* __restrict__ Ahi, const f16* __restrict__ Alo,
    const float* __restrict__ B, float* __restrict__ Cp,
    int K, int N, int Kc, int nMt, int nNt)
{
  __shared__ char sm[131072];                 // 2 x (Ahi 16K | Alo 16K | B 32K)
  const int t = threadIdx.x;
  const int lane = t & 63;
  const int wid = t >> 6;
  const int wr = wid >> 2;                    // 0..1 -> 128-row band
  const int wc = wid & 3;                     // 0..3 -> 64-col band
  const int rl = lane & 15;
  const int lq = lane >> 4;                   // 0..3 -> k-slot

  // block decode: XCD-grouped so the 4 nt-sharers of an A-chunk share bid%8
  int bid = blockIdx.x;
  int low = bid & 7, q = bid >> 3;
  int nt = q % nNt;
  int chi = q / nNt;
  int c = chi * 8 + low;
  int ks = c / nMt;
  int mt = c % nMt;
  const int brow = mt * 256;
  const int nbase = nt * 256;
  const int k0 = ks * Kc;
  const int nk = Kc >> 5;

  // staging offsets (A: pre-swizzled global source; LDS dest linear = lane*16)
  uint32_t aoffg[2], aldso[2];
#pragma unroll
  for (int i = 0; i < 2; ++i) {
    uint32_t idx = (uint32_t)t + 512u * i;    // 0..1023 -> (row, 16B seg)
    uint32_t r = idx >> 2, s = idx & 3;
    uint32_t sz = s ^ ((r >> 1) & 3);         // inverse of read-side XOR
    aoffg[i] = (uint32_t)(brow + r) * (uint32_t)K + sz * 8u;
    aldso[i] = idx * 16u;
  }
  uint32_t boffg[4], bldso[4];
#pragma unroll
  for (int i = 0; i < 4; ++i) {
    uint32_t idx = (uint32_t)t + 512u * i;    // 0..2047 -> (k-row, 16B seg of 256 f32)
    uint32_t kr = idx >> 6, sg = idx & 63;
    boffg[i] = kr * (uint32_t)N + (uint32_t)nbase + sg * 4u;
    bldso[i] = idx * 16u;
  }

  // fragment read offsets (A swizzled, B linear f32 [32][256])
  const uint32_t a_off = (uint32_t)((wr * 128 + rl) * 64) + (uint32_t)((lq ^ ((rl >> 1) & 3)) * 16);
  const uint32_t b_off = 32768u + (uint32_t)(lq * 8192) + (uint32_t)((wc * 64 + rl) * 4);

  f32x4 zero4 = {0.f, 0.f, 0.f, 0.f};
  f32x4 acc[8][4];
#pragma unroll
  for (int m = 0; m < 8; ++m)
#pragma unroll
    for (int n = 0; n < 4; ++n) acc[m][n] = zero4;

  auto STAGE = [&](int buf, int kt) {
    uint32_t kb = (uint32_t)(k0 + kt * 32);
    char* lb = sm + buf * 65536;
#pragma unroll
    for (int i = 0; i < 2; ++i) {
      gload16(Ahi + aoffg[i] + kb, lb + aldso[i]);
      gload16(Alo + aoffg[i] + kb, lb + 16384 + aldso[i]);
    }
#pragma unroll
    for (int i = 0; i < 4; ++i) {
      gload16(B + (size_t)kb * (uint32_t)N + boffg[i], lb + 32768 + bldso[i]);
    }
  };

  STAGE(0, 0);
  __syncthreads();
  int cur = 0;
  for (int kt = 0; kt < nk; ++kt) {
    if (kt + 1 < nk) STAGE(cur ^ 1, kt + 1);  // overlaps with compute below
    const char* lb = sm + cur * 65536;

    // build B fragments: fp32 -> (hi, lo*2^11) f16, flushed-hi split
    half8 bh[4], bl[4];
#pragma unroll
    for (int nf = 0; nf < 4; ++nf) {
#pragma unroll
      for (int jj = 0; jj < 8; ++jj) {
        float v = *(const float*)(lb + b_off + nf * 64 + jj * 1024);
        f16 hh = (f16)v;
        float hf = (float)hh;
        if (fabsf(hf) < 6.1035156e-5f) hf = 0.f;
        bh[nf][jj] = (f16)hf;
        bl[nf][jj] = (f16)((v - hf) * 2048.f);
      }
    }
#pragma unroll
    for (int m = 0; m < 8; ++m) {
      half8 ah = *(const half8*)(lb + a_off + m * 1024);
      half8 al = *(const half8*)(lb + 16384 + a_off + m * 1024);
#pragma unroll
      for (int nf = 0; nf < 4; ++nf) {
        acc[m][nf] = __builtin_amdgcn_mfma_f32_16x16x32_f16(ah, bh[nf], acc[m][nf], 0, 0, 0);
        f32x4 tt = __builtin_amdgcn_mfma_f32_16x16x32_f16(ah, bl[nf], zero4, 0, 0, 0);
        tt = __builtin_amdgcn_mfma_f32_16x16x32_f16(al, bh[nf], tt, 0, 0, 0);
        acc[m][nf] += tt * 4.8828125e-4f;     // 1/2048 fold of cross terms
      }
    }
    __syncthreads();                           // drains vmcnt(0)+lgkm + barrier
    cur ^= 1;
  }

  float* Cs = Cp + (size_t)ks * ((size_t)512 * (uint32_t)N);
#pragma unroll
  for (int m = 0; m < 8; ++m) {
    int rg = brow + wr * 128 + m * 16 + lq * 4;
#pragma unroll
    for (int nf = 0; nf < 4; ++nf) {
      int cg = nbase + wc * 64 + nf * 16 + rl;
#pragma unroll
      for (int rr = 0; rr < 4; ++rr)
        Cs[(size_t)(rg + rr) * (uint32_t)N + cg] = acc[m][nf][rr];
    }
  }
}

// ---------- reduce split-K partials (+bias, relu) -> f32 and/or f16 planes ----------
__global__ __launch_bounds__(256) void k_reduce(
    const float* __restrict__ parts, const float* __restrict__ bias,
    int nS, int MN, int Ncols, int relu,
    float* __restrict__ outf, f16* __restrict__ ohi, f16* __restrict__ olo)
{
  uint32_t idx = blockIdx.x * 256u + threadIdx.x;
  if (idx >= (uint32_t)MN) return;
  float s = bias[idx % (uint32_t)Ncols];
  for (int i = 0; i < nS; ++i) s += parts[(size_t)i * (uint32_t)MN + idx];
  if (relu) s = fmaxf(s, 0.f);
  if (outf) outf[idx] = s;
  if (ohi) { f16 h, l; splitf16(s, h, l); ohi[idx] = h; olo[idx] = l; }
}

// ---------- per-row softmax / label / score / box decode ----------
__global__ __launch_bounds__(256) void k_post(
    const float* __restrict__ ld, const float* __restrict__ prop,
    float* __restrict__ boxes, float* __restrict__ scores, int* __restrict__ labels)
{
  int n = blockIdx.x * 256 + threadIdx.x;
  if (n >= NBOX) return;
  const float* L = ld + (size_t)n * 512;
  float m = L[0];
  for (int j = 1; j < 81; ++j) m = fmaxf(m, L[j]);
  float sum = 0.f;
  for (int j = 0; j < 81; ++j) sum += expf(L[j] - m);
  float best = -1.f; int bj = 1;
  for (int j = 1; j < 81; ++j) {
    float p = expf(L[j] - m) / sum;            // mirror np softmax then argmax
    if (p > best) { best = p; bj = j; }
  }
  float d0 = L[81 + bj * 4 + 0];
  float d1 = L[81 + bj * 4 + 1];
  float d2 = L[81 + bj * 4 + 2];
  float d3 = L[81 + bj * 4 + 3];
  float p0 = prop[n * 4 + 0], p1 = prop[n * 4 + 1], p2 = prop[n * 4 + 2], p3 = prop[n * 4 + 3];
  float w = p2 - p0, h = p3 - p1;
  float cx = p0 + 0.5f * w, cy = p1 + 0.5f * h;
  float px = cx + d0 * w, py = cy + d1 * h;
  float pw = w * expf(fminf(fmaxf(d2, -4.f), 4.f));
  float ph = h * expf(fminf(fmaxf(d3, -4.f), 4.f));
  float bx0 = px - 0.5f * pw, by0 = py - 0.5f * ph;
  float bx1 = px + 0.5f * pw, by1 = py + 0.5f * ph;
  boxes[n * 4 + 0] = fminf(fmaxf(bx0, 0.f), 799.f);
  boxes[n * 4 + 1] = fminf(fmaxf(by0, 0.f), 799.f);
  boxes[n * 4 + 2] = fminf(fmaxf(bx1, 0.f), 799.f);
  boxes[n * 4 + 3] = fminf(fmaxf(by1, 0.f), 799.f);
  scores[n] = best;
  labels[n] = bj;
}

// ---------- stable descending bitonic sort (key = ~scorebits : idx) ----------
__global__ __launch_bounds__(512) void k_sort(
    const float* __restrict__ scores, const float* __restrict__ boxes, const int* __restrict__ labels,
    float* __restrict__ bs, float* __restrict__ ss, int* __restrict__ ls)
{
  __shared__ unsigned long long keys[512];
  int t = threadIdx.x;
  unsigned sb = __float_as_uint(scores[t]);    // scores > 0 -> bits monotone
  keys[t] = ((unsigned long long)(0xFFFFFFFFu - sb) << 32) | (unsigned)t;
  __syncthreads();
  for (int k = 2; k <= 512; k <<= 1) {
    for (int j = k >> 1; j > 0; j >>= 1) {
      int p = t ^ j;
      if (p > t) {
        unsigned long long a = keys[t], b = keys[p];
        bool asc = ((t & k) == 0);
        if (asc ? (a > b) : (a < b)) { keys[t] = b; keys[p] = a; }
      }
      __syncthreads();
    }
  }
  unsigned o = (unsigned)(keys[t] & 0xFFFFFFFFu);
  ss[t] = scores[o];
  ls[t] = labels[o];
  bs[t * 4 + 0] = boxes[o * 4 + 0];
  bs[t * 4 + 1] = boxes[o * 4 + 1];
  bs[t * 4 + 2] = boxes[o * 4 + 2];
  bs[t * 4 + 3] = boxes[o * 4 + 3];
}

// ---------- IoU suppression bitmask: mask[i][w] bit l = (iou(i, w*64+l)>TH && j>i) ----------
__global__ __launch_bounds__(64) void k_mask(const float* __restrict__ bs,
                                             unsigned long long* __restrict__ mask) {
  int i = blockIdx.x;
  int lane = threadIdx.x;
  float ax0 = bs[i * 4], ay0 = bs[i * 4 + 1], ax1 = bs[i * 4 + 2], ay1 = bs[i * 4 + 3];
  float aarea = fmaxf(ax1 - ax0, 0.f) * fmaxf(ay1 - ay0, 0.f);
  for (int w = 0; w < 8; ++w) {
    int j = w * 64 + lane;
    float bx0 = bs[j * 4], by0 = bs[j * 4 + 1], bx1 = bs[j * 4 + 2], by1 = bs[j * 4 + 3];
    float barea = fmaxf(bx1 - bx0, 0.f) * fmaxf(by1 - by0, 0.f);
    float ix0 = fmaxf(ax0, bx0), iy0 = fmaxf(ay0, by0);
    float ix1 = fminf(ax1, bx1), iy1 = fminf(ay1, by1);
    float inter = fmaxf(ix1 - ix0, 0.f) * fmaxf(iy1 - iy0, 0.f);
    float iou = inter / (aarea + barea - inter + 1e-6f);
    bool cond = (iou > 0.5f) && (j > i);
    unsigned long long b = __ballot(cond);
    if (lane == 0) mask[i * 8 + w] = b;
  }
}

// ---------- sequential NMS on bitmasks + final output assembly ----------
__global__ __launch_bounds__(64) void k_nms(const unsigned long long* __restrict__ mask,
                                            const float* __restrict__ ss,
                                            const float* __restrict__ bs,
                                            const int* __restrict__ ls,
                                            float* __restrict__ out) {
  int lane = threadIdx.x;
  unsigned long long bal[8];
  for (int w = 0; w < 8; ++w) bal[w] = __ballot(ss[w * 64 + lane] > 0.05f);
  unsigned long long keep = (lane < 8) ? bal[lane] : 0ULL;
  for (int i = 0; i < 512; ++i) {
    unsigned long long kw = __shfl(keep, i >> 6);
    if ((kw >> (i & 63)) & 1ULL) {
      unsigned long long mi = (lane < 8) ? mask[i * 8 + lane] : 0ULL;
      keep &= ~mi;
    }
  }
  __shared__ unsigned long long kws[8];
  if (lane < 8) kws[lane] = keep;
  __syncthreads();
  for (int it = 0; it < 56; ++it) {
    int idx = lane + it * 64;                  // 0..3583
    float val;
    if (idx < 2560) {
      int i = idx / 5, c2 = idx % 5;
      bool kb = (kws[i >> 6] >> (i & 63)) & 1ULL;
      val = kb ? (c2 < 4 ? bs[i * 4 + c2] : ss[i]) : 0.f;
    } else if (idx < 3072) {
      int i = idx - 2560;
      val = (float)ls[i];
    } else {
      int i = idx - 3072;
      val = ((kws[i >> 6] >> (i & 63)) & 1ULL) ? 1.f : 0.f;
    }
    out[idx] = val;
  }
}

// ---------- workspace layout ----------
static constexpr size_t SZ_X    = (size_t)NBOX * D1 * 2;            // 51,380,224
static constexpr size_t OFF_XHI = 0;
static constexpr size_t OFF_XLO = OFF_XHI + SZ_X;
static constexpr size_t OFF_PART = OFF_XLO + SZ_X;
static constexpr size_t SZ_PART = (size_t)32 * 512 * 1024 * 4;      // 67,108,864
static constexpr size_t SZ_H    = (size_t)512 * 1024 * 2;
static constexpr size_t OFF_H1HI = OFF_PART + SZ_PART;
static constexpr size_t OFF_H1LO = OFF_H1HI + SZ_H;
static constexpr size_t OFF_H2HI = OFF_H1LO + SZ_H;
static constexpr size_t OFF_H2LO = OFF_H2HI + SZ_H;
static constexpr size_t OFF_WH   = OFF_H2LO + SZ_H;                 // 1024*512*4
static constexpr size_t OFF_BH   = OFF_WH + (size_t)1024 * 512 * 4;
static constexpr size_t OFF_LD   = OFF_BH + 4096;                   // 512*512*4
static constexpr size_t OFF_BOX  = OFF_LD + (size_t)512 * 512 * 4;
static constexpr size_t OFF_SC   = OFF_BOX + 512 * 4 * 4;
static constexpr size_t OFF_LB   = OFF_SC + 4096;
static constexpr size_t OFF_BS   = OFF_LB + 4096;
static constexpr size_t OFF_SS   = OFF_BS + 512 * 4 * 4;
static constexpr size_t OFF_LS   = OFF_SS + 4096;
static constexpr size_t OFF_MASK = OFF_LS + 4096;
static constexpr size_t OFF_END  = OFF_MASK + (size_t)512 * 8 * 8;

extern "C" void kernel_launch(void* const* d_in, const int* in_sizes, int n_in,
                              void* d_out, int out_size, void* d_ws, size_t ws_size,
                              hipStream_t stream)
{
  (void)in_sizes; (void)n_in;
  const float* feat = (const float*)d_in[0];
  const float* prop = (const float*)d_in[1];
  const float* w1   = (const float*)d_in[2];
  const float* b1   = (const float*)d_in[3];
  const float* w2   = (const float*)d_in[4];
  const float* b2   = (const float*)d_in[5];
  const float* wcls = (const float*)d_in[6];
  const float* bcls = (const float*)d_in[7];
  const float* wreg = (const float*)d_in[8];
  const float* breg = (const float*)d_in[9];
  float* out = (float*)d_out;
  char* W = (char*)d_ws;

  if (ws_size < OFF_END) {                     // sentinel: workspace too small
    hipMemsetAsync(out, 0x7f, (size_t)out_size * 4, stream);
    return;
  }

  f16*   xhi   = (f16*)(W + OFF_XHI);
  f16*   xlo   = (f16*)(W + OFF_XLO);
  float* parts = (float*)(W + OFF_PART);
  f16*   h1hi  = (f16*)(W + OFF_H1HI);
  f16*   h1lo  = (f16*)(W + OFF_H1LO);
  f16*   h2hi  = (f16*)(W + OFF_H2HI);
  f16*   h2lo  = (f16*)(W + OFF_H2LO);
  float* whead = (float*)(W + OFF_WH);
  float* bhead = (float*)(W + OFF_BH);
  float* ldbuf = (float*)(W + OFF_LD);
  float* boxes = (float*)(W + OFF_BOX);
  float* scores= (float*)(W + OFF_SC);
  int*   labels= (int*)(W + OFF_LB);
  float* bsrt  = (float*)(W + OFF_BS);
  float* ssrt  = (float*)(W + OFF_SS);
  int*   lsrt  = (int*)(W + OFF_LS);
  unsigned long long* maskb = (unsigned long long*)(W + OFF_MASK);

  k_pack<<<2050, 256, 0, stream>>>(wcls, bcls, wreg, breg, whead, bhead);
  k_roi<<<(NBOX * D1) / 256, 256, 0, stream>>>(feat, prop, xhi, xlo);

  // FC1: M=512 N=1024 K=50176, Kc=1568, grid 2*4*32=256
  k_gemm<<<256, 512, 0, stream>>>(xhi, xlo, w1, parts, D1, 1024, 1568, 2, 4);
  k_reduce<<<2048, 256, 0, stream>>>(parts, b1, 32, 512 * 1024, 1024, 1, nullptr, h1hi, h1lo);

  // FC2: K=1024, Kc=128, grid 2*4*8=64
  k_gemm<<<64, 512, 0, stream>>>(h1hi, h1lo, w2, parts, 1024, 1024, 128, 2, 4);
  k_reduce<<<2048, 256, 0, stream>>>(parts, b2, 8, 512 * 1024, 1024, 1, nullptr, h2hi, h2lo);

  // heads: N=512 (81 logits | 324 deltas | pad), Kc=64, grid 2*2*16=64
  k_gemm<<<64, 512, 0, stream>>>(h2hi, h2lo, whead, parts, 1024, 512, 64, 2, 2);
  k_reduce<<<1024, 256, 0, stream>>>(parts, bhead, 16, 512 * 512, 512, 0, ldbuf, nullptr, nullptr);

  k_post<<<2, 256, 0, stream>>>(ldbuf, prop, boxes, scores, labels);
  k_sort<<<1, 512, 0, stream>>>(scores, boxes, labels, bsrt, ssrt, lsrt);
  k_mask<<<512, 64, 0, stream>>>(bsrt, maskb);
  k_nms<<<1, 64, 0, stream>>>(maskb, ssrt, bsrt, lsrt, out);
}

// Round 3
// 415.775 us; speedup vs baseline: 1.0492x; 1.0492x over previous
//
#include <hip/hip_runtime.h>
#include <cstdint>

#define F_H 200
#define F_W 200
#define D1  50176
#define NBOX 512
#define NHID 1024

typedef _Float16 f16;
typedef _Float16 half8 __attribute__((ext_vector_type(8)));
typedef _Float16 half4v __attribute__((ext_vector_type(4)));
typedef _Float16 half2v __attribute__((ext_vector_type(2)));
typedef float    f32x4 __attribute__((ext_vector_type(4)));

// ---------- helpers ----------
__device__ __forceinline__ void gload16(const void* g, void* l) {
  __builtin_amdgcn_global_load_lds((const __attribute__((address_space(1))) void*)g,
                                   (__attribute__((address_space(3))) void*)l,
                                   16, 0, 0);
}

__device__ __forceinline__ half2v pkrtz(float a, float b) {
  return __builtin_bit_cast(half2v, __builtin_amdgcn_cvt_pkrtz(a, b));
}

// f32 -> f16 hi + f16 lo*2^-11 split; flush sub-normal hi so result is identical
// regardless of MFMA input-denormal behavior.
__device__ __forceinline__ void splitf16(float v, f16& h, f16& l) {
  f16 hh = (f16)v;
  float hf = (float)hh;
  if (fabsf(hf) < 6.1035156e-5f) hf = 0.f;
  h = (f16)hf;
  l = (f16)((v - hf) * 2048.f);
}

// ---------- ROI align + split (2 outputs per thread, 4B stores) ----------
__global__ __launch_bounds__(256) void k_roi(const float* __restrict__ feat,
                                             const float* __restrict__ prop,
                                             f16* __restrict__ xhi, f16* __restrict__ xlo) {
  uint32_t idx = blockIdx.x * 256u + threadIdx.x;      // < 512*256*98 exactly
  uint32_t n = idx / 25088u;
  uint32_t rem = idx % 25088u;
  uint32_t c = rem / 98u;
  uint32_t r2 = rem % 98u;
  uint32_t i = r2 / 7u;
  uint32_t jp = r2 % 7u;
  float b0 = prop[n * 4 + 0] * 0.25f, b1 = prop[n * 4 + 1] * 0.25f;
  float b2 = prop[n * 4 + 2] * 0.25f, b3 = prop[n * 4 + 3] * 0.25f;
  float ty = ((float)i + 0.5f) * (1.0f / 14.0f);
  float yy = b1 + (b3 - b1) * ty;
  float y0f = floorf(yy);
  float fy = yy - y0f;
  int y0 = (int)y0f; y0 = y0 < 0 ? 0 : (y0 > F_H - 1 ? F_H - 1 : y0);
  int y1 = y0 + 1 > F_H - 1 ? F_H - 1 : y0 + 1;
  const float* fr0 = feat + (size_t)c * (F_H * F_W) + (size_t)y0 * F_W;
  const float* fr1 = feat + (size_t)c * (F_H * F_W) + (size_t)y1 * F_W;
  f16 hs[2], ls[2];
#pragma unroll
  for (int e = 0; e < 2; ++e) {
    uint32_t j = jp * 2u + (uint32_t)e;
    float tx = ((float)j + 0.5f) * (1.0f / 14.0f);
    float xx = b0 + (b2 - b0) * tx;
    float x0f = floorf(xx);
    float fx = xx - x0f;
    int x0 = (int)x0f; x0 = x0 < 0 ? 0 : (x0 > F_W - 1 ? F_W - 1 : x0);
    int x1 = x0 + 1 > F_W - 1 ? F_W - 1 : x0 + 1;
    float v00 = fr0[x0], v01 = fr0[x1], v10 = fr1[x0], v11 = fr1[x1];
    float v = (1.f - fx) * (1.f - fy) * v00 + fx * (1.f - fy) * v01 +
              (1.f - fx) * fy * v10 + fx * fy * v11;
    splitf16(v, hs[e], ls[e]);
  }
  uint32_t base = n * 50176u + c * 196u + i * 14u + jp * 2u;
  half2v hv; hv[0] = hs[0]; hv[1] = hs[1];
  half2v lv; lv[0] = ls[0]; lv[1] = ls[1];
  *(half2v*)(xhi + base) = hv;
  *(half2v*)(xlo + base) = lv;
}

// ---------- pack [w_cls | w_reg | 0] -> [1024][512] and bias ----------
__global__ __launch_bounds__(256) void k_pack(const float* __restrict__ wc, const float* __restrict__ bc,
                                              const float* __restrict__ wr, const float* __restrict__ br,
                                              float* __restrict__ wh, float* __restrict__ bh) {
  uint32_t idx = blockIdx.x * 256u + threadIdx.x;
  if (idx < (uint32_t)NHID * 512u) {
    uint32_t k = idx >> 9, n = idx & 511u;
    float v = 0.f;
    if (n < 81u) v = wc[k * 81u + n];
    else if (n < 405u) v = wr[k * 324u + (n - 81u)];
    wh[idx] = v;
  } else if (idx < (uint32_t)NHID * 512u + 512u) {
    uint32_t n = idx - (uint32_t)NHID * 512u;
    float v = 0.f;
    if (n < 81u) v = bc[n];
    else if (n < 405u) v = br[n - 81u];
    bh[n] = v;
  }
}

// ---------- split-f16 GEMM, 256x256 tile, BK=32, 2-phase counted-vmcnt pipeline ----------
// LDS buf (64KB): [0,16K) Ahi [256][64B swz] | [16K,32K) Alo | [32K,64K) B as [half][32][512B swz]
__global__ __launch_bounds__(512, 2) void k_gemm(
    const f16* __restrict__ Ahi, const f16* __restrict__ Alo,
    const float* __restrict__ B, float* __restrict__ Cp,
    int K, int N, int Kc, int nMt, int nNt)
{
  __shared__ char sm[131072];
  const int t = threadIdx.x;
  const int lane = t & 63;
  const int wid = t >> 6;
  const int wr = wid >> 2;                    // 0..1 -> 128-row band
  const int wc = wid & 3;                    // 0..3 -> 16-col interleave within 64-col nf band
  const int rl = lane & 15;
  const int lq = lane >> 4;

  // block decode: XCD-grouped so the nt-sharers of an A-chunk share bid%8
  int bid = blockIdx.x;
  int low = bid & 7, q = bid >> 3;
  int nt = q % nNt;
  int chi = q / nNt;
  int c = chi * 8 + low;
  int ks = c / nMt;
  int mt = c % nMt;
  const int brow = mt * 256;
  const int nbase = nt * 256;
  const int k0 = ks * Kc;
  const int nk = Kc >> 5;

  // A staging offsets (pre-swizzled global source; LDS dest linear)
  uint32_t aoffg[2], aldso[2];
#pragma unroll
  for (int i = 0; i < 2; ++i) {
    uint32_t idx = (uint32_t)t + 512u * i;    // 0..1023 -> (row, 16B seg)
    uint32_t r = idx >> 2, s = idx & 3;
    uint32_t sz = s ^ ((r >> 1) & 3);         // inverse of read-side XOR
    aoffg[i] = (uint32_t)(brow + r) * (uint32_t)K + sz * 8u;
    aldso[i] = idx * 16u;
  }
  // B staging: two 128-col halves, [h][32 rows][512B]; source seg pre-swizzled by k-row
  uint32_t boffg[2][2], bldso[2][2];
#pragma unroll
  for (int h = 0; h < 2; ++h)
#pragma unroll
    for (int i = 0; i < 2; ++i) {
      uint32_t idx = (uint32_t)t + 512u * i;  // 0..1023 segs of this half
      uint32_t kr = idx >> 5, sg = idx & 31;
      uint32_t sgs = sg ^ (((kr >> 3) & 3) << 2);
      boffg[h][i] = kr * (uint32_t)N + (uint32_t)(nbase + h * 128) + sgs * 4u;
      bldso[h][i] = 32768u + (uint32_t)h * 16384u + idx * 16u;
    }

  const uint32_t a_off = (uint32_t)(wr * 8192 + rl * 64) + (uint32_t)((lq ^ ((rl >> 1) & 3)) * 16);
  // B element byte addr within half: ((wc^lq)*16 + rl)*4 col part (XOR read-side swizzle)
  const uint32_t b_lane = (uint32_t)((((wc ^ lq) & 3) * 16 + rl) * 4);

  f32x4 zero4 = {0.f, 0.f, 0.f, 0.f};
  f32x4 acc[8][4];
#pragma unroll
  for (int m = 0; m < 8; ++m)
#pragma unroll
    for (int n = 0; n < 4; ++n) acc[m][n] = zero4;

#define STAGE_A(LB, KB) do { \
    gload16(Ahi + aoffg[0] + (KB), (LB) + aldso[0]); \
    gload16(Alo + aoffg[0] + (KB), (LB) + 16384 + aldso[0]); \
    gload16(Ahi + aoffg[1] + (KB), (LB) + aldso[1]); \
    gload16(Alo + aoffg[1] + (KB), (LB) + 16384 + aldso[1]); \
  } while (0)

#define STAGE_B(LB, KB) do { \
    gload16(B + (size_t)(KB) * (uint32_t)N + boffg[0][0], (LB) + bldso[0][0]); \
    gload16(B + (size_t)(KB) * (uint32_t)N + boffg[0][1], (LB) + bldso[0][1]); \
    gload16(B + (size_t)(KB) * (uint32_t)N + boffg[1][0], (LB) + bldso[1][0]); \
    gload16(B + (size_t)(KB) * (uint32_t)N + boffg[1][1], (LB) + bldso[1][1]); \
  } while (0)

#define COMPUTE_PHASE(P) do { \
    half8 bhv[2], blv[2]; \
    _Pragma("unroll") \
    for (int x = 0; x < 2; ++x) { \
      const int nf = 2 * (P) + x; \
      const char* bb = lb + 32768 + (nf >> 1) * 16384 + (nf & 1) * 256 + b_lane; \
      _Pragma("unroll") \
      for (int jj = 0; jj < 8; jj += 2) { \
        float v0 = *(const float*)(bb + (lq * 8 + jj) * 512); \
        float v1 = *(const float*)(bb + (lq * 8 + jj + 1) * 512); \
        half2v hp = pkrtz(v0, v1); \
        f16 e0 = (fabsf(v0) >= 6.1035156e-5f) ? hp[0] : (f16)0; \
        f16 e1 = (fabsf(v1) >= 6.1035156e-5f) ? hp[1] : (f16)0; \
        half2v lp = pkrtz((v0 - (float)e0) * 2048.f, (v1 - (float)e1) * 2048.f); \
        bhv[x][jj] = e0; bhv[x][jj + 1] = e1; \
        blv[x][jj] = lp[0]; blv[x][jj + 1] = lp[1]; \
      } \
    } \
    __builtin_amdgcn_s_setprio(1); \
    _Pragma("unroll") \
    for (int m = 0; m < 8; ++m) { \
      half8 ah = *(const half8*)(lb + a_off + m * 1024); \
      half8 al = *(const half8*)(lb + 16384 + a_off + m * 1024); \
      _Pragma("unroll") \
      for (int x = 0; x < 2; ++x) { \
        const int nf = 2 * (P) + x; \
        acc[m][nf] = __builtin_amdgcn_mfma_f32_16x16x32_f16(ah, bhv[x], acc[m][nf], 0, 0, 0); \
        f32x4 tt = __builtin_amdgcn_mfma_f32_16x16x32_f16(ah, blv[x], zero4, 0, 0, 0); \
        tt = __builtin_amdgcn_mfma_f32_16x16x32_f16(al, bhv[x], tt, 0, 0, 0); \
        acc[m][nf] += tt * 4.8828125e-4f; \
      } \
    } \
    __builtin_amdgcn_s_setprio(0); \
  } while (0)

  // prologue: stage tile 0 into buf 0 (issue order: A then B-half0 then B-half1)
  STAGE_A(sm, (uint32_t)k0);
  STAGE_B(sm, (uint32_t)k0);

  int cur = 0;
  for (int kt = 0; kt < nk; ++kt) {
    int ktn = (kt + 1 < nk) ? kt + 1 : kt;    // clamp keeps vmcnt counts uniform
    uint32_t kbn = (uint32_t)(k0 + ktn * 32);
    const char* lb = sm + cur * 65536;
    char* lbn = sm + (cur ^ 1) * 65536;

    // ---- phase 0: needs A(t) + Bhalf0(t); Bhalf1(t) may still be in flight ----
    asm volatile("s_waitcnt vmcnt(2)" ::: "memory");
    __builtin_amdgcn_s_barrier();
    __builtin_amdgcn_sched_barrier(0);
    STAGE_A(lbn, kbn);                        // A(t+1): 4 loads in flight
    COMPUTE_PHASE(0);

    // ---- phase 1: needs Bhalf1(t); A(t+1) (4 loads) may still be in flight ----
    asm volatile("s_waitcnt vmcnt(4)" ::: "memory");
    __builtin_amdgcn_s_barrier();
    __builtin_amdgcn_sched_barrier(0);
    STAGE_B(lbn, kbn);                        // B(t+1): 4 loads in flight
    COMPUTE_PHASE(1);

    cur ^= 1;
  }

  float* Cs = Cp + (size_t)ks * ((size_t)512 * (uint32_t)N);
#pragma unroll
  for (int m = 0; m < 8; ++m) {
    int rg = brow + wr * 128 + m * 16 + lq * 4;
#pragma unroll
    for (int nf = 0; nf < 4; ++nf) {
      int cg = nbase + nf * 64 + wc * 16 + rl;
#pragma unroll
      for (int rr = 0; rr < 4; ++rr)
        Cs[(size_t)(rg + rr) * (uint32_t)N + cg] = acc[m][nf][rr];
    }
  }
#undef STAGE_A
#undef STAGE_B
#undef COMPUTE_PHASE
}

// ---------- reduce split-K partials (+bias, relu), float4 vectorized ----------
__global__ __launch_bounds__(256) void k_reduce(
    const float* __restrict__ parts, const float* __restrict__ bias,
    int nS, int MN4, int Ncols, int relu,
    float* __restrict__ outf, f16* __restrict__ ohi, f16* __restrict__ olo)
{
  uint32_t idx = blockIdx.x * 256u + threadIdx.x;
  if (idx >= (uint32_t)MN4) return;
  f32x4 s = *(const f32x4*)(bias + ((idx * 4u) % (uint32_t)Ncols));
  const f32x4* p4 = (const f32x4*)parts;
  for (int i = 0; i < nS; ++i) s += p4[(size_t)i * (uint32_t)MN4 + idx];
  if (relu) {
#pragma unroll
    for (int j = 0; j < 4; ++j) s[j] = fmaxf(s[j], 0.f);
  }
  if (outf) *(f32x4*)(outf + (size_t)idx * 4) = s;
  if (ohi) {
    half4v h, l;
#pragma unroll
    for (int j = 0; j < 4; ++j) { f16 hh, ll; splitf16(s[j], hh, ll); h[j] = hh; l[j] = ll; }
    *(half4v*)(ohi + (size_t)idx * 4) = h;
    *(half4v*)(olo + (size_t)idx * 4) = l;
  }
}

// ---------- per-row softmax / label / score / box decode ----------
__global__ __launch_bounds__(256) void k_post(
    const float* __restrict__ ld, const float* __restrict__ prop,
    float* __restrict__ boxes, float* __restrict__ scores, int* __restrict__ labels)
{
  int n = blockIdx.x * 256 + threadIdx.x;
  if (n >= NBOX) return;
  const float* L = ld + (size_t)n * 512;
  float m = L[0];
  for (int j = 1; j < 81; ++j) m = fmaxf(m, L[j]);
  float sum = 0.f;
  for (int j = 0; j < 81; ++j) sum += expf(L[j] - m);
  float best = -1.f; int bj = 1;
  for (int j = 1; j < 81; ++j) {
    float p = expf(L[j] - m) / sum;            // mirror np softmax then argmax
    if (p > best) { best = p; bj = j; }
  }
  float d0 = L[81 + bj * 4 + 0];
  float d1 = L[81 + bj * 4 + 1];
  float d2 = L[81 + bj * 4 + 2];
  float d3 = L[81 + bj * 4 + 3];
  float p0 = prop[n * 4 + 0], p1 = prop[n * 4 + 1], p2 = prop[n * 4 + 2], p3 = prop[n * 4 + 3];
  float w = p2 - p0, h = p3 - p1;
  float cx = p0 + 0.5f * w, cy = p1 + 0.5f * h;
  float px = cx + d0 * w, py = cy + d1 * h;
  float pw = w * expf(fminf(fmaxf(d2, -4.f), 4.f));
  float ph = h * expf(fminf(fmaxf(d3, -4.f), 4.f));
  float bx0 = px - 0.5f * pw, by0 = py - 0.5f * ph;
  float bx1 = px + 0.5f * pw, by1 = py + 0.5f * ph;
  boxes[n * 4 + 0] = fminf(fmaxf(bx0, 0.f), 799.f);
  boxes[n * 4 + 1] = fminf(fmaxf(by0, 0.f), 799.f);
  boxes[n * 4 + 2] = fminf(fmaxf(bx1, 0.f), 799.f);
  boxes[n * 4 + 3] = fminf(fmaxf(by1, 0.f), 799.f);
  scores[n] = best;
  labels[n] = bj;
}

// ---------- stable descending bitonic sort (key = ~scorebits : idx) ----------
__global__ __launch_bounds__(512) void k_sort(
    const float* __restrict__ scores, const float* __restrict__ boxes, const int* __restrict__ labels,
    float* __restrict__ bs, float* __restrict__ ss, int* __restrict__ ls)
{
  __shared__ unsigned long long keys[512];
  int t = threadIdx.x;
  unsigned sb = __float_as_uint(scores[t]);    // scores > 0 -> bits monotone
  keys[t] = ((unsigned long long)(0xFFFFFFFFu - sb) << 32) | (unsigned)t;
  __syncthreads();
  for (int k = 2; k <= 512; k <<= 1) {
    for (int j = k >> 1; j > 0; j >>= 1) {
      int p = t ^ j;
      if (p > t) {
        unsigned long long a = keys[t], b = keys[p];
        bool asc = ((t & k) == 0);
        if (asc ? (a > b) : (a < b)) { keys[t] = b; keys[p] = a; }
      }
      __syncthreads();
    }
  }
  unsigned o = (unsigned)(keys[t] & 0xFFFFFFFFu);
  ss[t] = scores[o];
  ls[t] = labels[o];
  bs[t * 4 + 0] = boxes[o * 4 + 0];
  bs[t * 4 + 1] = boxes[o * 4 + 1];
  bs[t * 4 + 2] = boxes[o * 4 + 2];
  bs[t * 4 + 3] = boxes[o * 4 + 3];
}

// ---------- IoU suppression bitmask ----------
__global__ __launch_bounds__(64) void k_mask(const float* __restrict__ bs,
                                             unsigned long long* __restrict__ mask) {
  int i = blockIdx.x;
  int lane = threadIdx.x;
  float ax0 = bs[i * 4], ay0 = bs[i * 4 + 1], ax1 = bs[i * 4 + 2], ay1 = bs[i * 4 + 3];
  float aarea = fmaxf(ax1 - ax0, 0.f) * fmaxf(ay1 - ay0, 0.f);
  for (int w = 0; w < 8; ++w) {
    int j = w * 64 + lane;
    float bx0 = bs[j * 4], by0 = bs[j * 4 + 1], bx1 = bs[j * 4 + 2], by1 = bs[j * 4 + 3];
    float barea = fmaxf(bx1 - bx0, 0.f) * fmaxf(by1 - by0, 0.f);
    float ix0 = fmaxf(ax0, bx0), iy0 = fmaxf(ay0, by0);
    float ix1 = fminf(ax1, bx1), iy1 = fminf(ay1, by1);
    float inter = fmaxf(ix1 - ix0, 0.f) * fmaxf(iy1 - iy0, 0.f);
    float iou = inter / (aarea + barea - inter + 1e-6f);
    bool cond = (iou > 0.5f) && (j > i);
    unsigned long long b = __ballot(cond);
    if (lane == 0) mask[i * 8 + w] = b;
  }
}

// ---------- sequential NMS on bitmasks + final output assembly ----------
__global__ __launch_bounds__(64) void k_nms(const unsigned long long* __restrict__ mask,
                                            const float* __restrict__ ss,
                                            const float* __restrict__ bs,
                                            const int* __restrict__ ls,
                                            float* __restrict__ out) {
  int lane = threadIdx.x;
  unsigned long long bal[8];
  for (int w = 0; w < 8; ++w) bal[w] = __ballot(ss[w * 64 + lane] > 0.05f);
  unsigned long long keep = (lane < 8) ? bal[lane] : 0ULL;
  for (int i = 0; i < 512; ++i) {
    unsigned long long kw = __shfl(keep, i >> 6);
    if ((kw >> (i & 63)) & 1ULL) {
      unsigned long long mi = (lane < 8) ? mask[i * 8 + lane] : 0ULL;
      keep &= ~mi;
    }
  }
  __shared__ unsigned long long kws[8];
  if (lane < 8) kws[lane] = keep;
  __syncthreads();
  for (int it = 0; it < 56; ++it) {
    int idx = lane + it * 64;                  // 0..3583
    float val;
    if (idx < 2560) {
      int i = idx / 5, c2 = idx % 5;
      bool kb = (kws[i >> 6] >> (i & 63)) & 1ULL;
      val = kb ? (c2 < 4 ? bs[i * 4 + c2] : ss[i]) : 0.f;
    } else if (idx < 3072) {
      int i = idx - 2560;
      val = (float)ls[i];
    } else {
      int i = idx - 3072;
      val = ((kws[i >> 6] >> (i & 63)) & 1ULL) ? 1.f : 0.f;
    }
    out[idx] = val;
  }
}

// ---------- workspace layout ----------
static constexpr size_t SZ_X    = (size_t)NBOX * D1 * 2;            // 51,380,224
static constexpr size_t OFF_XHI = 0;
static constexpr size_t OFF_XLO = OFF_XHI + SZ_X;
static constexpr size_t OFF_PART = OFF_XLO + SZ_X;
static constexpr size_t SZ_PART = (size_t)32 * 512 * 1024 * 4;      // 67,108,864
static constexpr size_t SZ_H    = (size_t)512 * 1024 * 2;
static constexpr size_t OFF_H1HI = OFF_PART + SZ_PART;
static constexpr size_t OFF_H1LO = OFF_H1HI + SZ_H;
static constexpr size_t OFF_H2HI = OFF_H1LO + SZ_H;
static constexpr size_t OFF_H2LO = OFF_H2HI + SZ_H;
static constexpr size_t OFF_WH   = OFF_H2LO + SZ_H;                 // 1024*512*4
static constexpr size_t OFF_BH   = OFF_WH + (size_t)1024 * 512 * 4;
static constexpr size_t OFF_LD   = OFF_BH + 4096;                   // 512*512*4
static constexpr size_t OFF_BOX  = OFF_LD + (size_t)512 * 512 * 4;
static constexpr size_t OFF_SC   = OFF_BOX + 512 * 4 * 4;
static constexpr size_t OFF_LB   = OFF_SC + 4096;
static constexpr size_t OFF_BS   = OFF_LB + 4096;
static constexpr size_t OFF_SS   = OFF_BS + 512 * 4 * 4;
static constexpr size_t OFF_LS   = OFF_SS + 4096;
static constexpr size_t OFF_MASK = OFF_LS + 4096;
static constexpr size_t OFF_END  = OFF_MASK + (size_t)512 * 8 * 8;

extern "C" void kernel_launch(void* const* d_in, const int* in_sizes, int n_in,
                              void* d_out, int out_size, void* d_ws, size_t ws_size,
                              hipStream_t stream)
{
  (void)in_sizes; (void)n_in;
  const float* feat = (const float*)d_in[0];
  const float* prop = (const float*)d_in[1];
  const float* w1   = (const float*)d_in[2];
  const float* b1   = (const float*)d_in[3];
  const float* w2   = (const float*)d_in[4];
  const float* b2   = (const float*)d_in[5];
  const float* wcls = (const float*)d_in[6];
  const float* bcls = (const float*)d_in[7];
  const float* wreg = (const float*)d_in[8];
  const float* breg = (const float*)d_in[9];
  float* out = (float*)d_out;
  char* W = (char*)d_ws;

  if (ws_size < OFF_END) {                     // sentinel: workspace too small
    (void)hipMemsetAsync(out, 0x7f, (size_t)out_size * 4, stream);
    return;
  }

  f16*   xhi   = (f16*)(W + OFF_XHI);
  f16*   xlo   = (f16*)(W + OFF_XLO);
  float* parts = (float*)(W + OFF_PART);
  f16*   h1hi  = (f16*)(W + OFF_H1HI);
  f16*   h1lo  = (f16*)(W + OFF_H1LO);
  f16*   h2hi  = (f16*)(W + OFF_H2HI);
  f16*   h2lo  = (f16*)(W + OFF_H2LO);
  float* whead = (float*)(W + OFF_WH);
  float* bhead = (float*)(W + OFF_BH);
  float* ldbuf = (float*)(W + OFF_LD);
  float* boxes = (float*)(W + OFF_BOX);
  float* scores= (float*)(W + OFF_SC);
  int*   labels= (int*)(W + OFF_LB);
  float* bsrt  = (float*)(W + OFF_BS);
  float* ssrt  = (float*)(W + OFF_SS);
  int*   lsrt  = (int*)(W + OFF_LS);
  unsigned long long* maskb = (unsigned long long*)(W + OFF_MASK);

  k_pack<<<2050, 256, 0, stream>>>(wcls, bcls, wreg, breg, whead, bhead);
  k_roi<<<50176, 256, 0, stream>>>(feat, prop, xhi, xlo);

  // FC1: M=512 N=1024 K=50176, Kc=1568, grid 2*4*32=256
  k_gemm<<<256, 512, 0, stream>>>(xhi, xlo, w1, parts, D1, 1024, 1568, 2, 4);
  k_reduce<<<512, 256, 0, stream>>>(parts, b1, 32, 131072, 1024, 1, nullptr, h1hi, h1lo);

  // FC2: K=1024, Kc=128, grid 2*4*8=64
  k_gemm<<<64, 512, 0, stream>>>(h1hi, h1lo, w2, parts, 1024, 1024, 128, 2, 4);
  k_reduce<<<512, 256, 0, stream>>>(parts, b2, 8, 131072, 1024, 1, nullptr, h2hi, h2lo);

  // heads: N=512 (81 logits | 324 deltas | pad), Kc=64, grid 2*2*16=64
  k_gemm<<<64, 512, 0, stream>>>(h2hi, h2lo, whead, parts, 1024, 512, 64, 2, 2);
  k_reduce<<<256, 256, 0, stream>>>(parts, bhead, 16, 65536, 512, 0, ldbuf, nullptr, nullptr);

  k_post<<<2, 256, 0, stream>>>(ldbuf, prop, boxes, scores, labels);
  k_sort<<<1, 512, 0, stream>>>(scores, boxes, labels, bsrt, ssrt, lsrt);
  k_mask<<<512, 64, 0, stream>>>(bsrt, maskb);
  k_nms<<<1, 64, 0, stream>>>(maskb, ssrt, bsrt, lsrt, out);
}